// Round 7
// baseline (538.174 us; speedup 1.0000x reference)
//
#include <hip/hip_runtime.h>
#include <stdint.h>

// B=32, N=4096, D=256, S=8, H_MLP=512, 3 iterations.

typedef __attribute__((ext_vector_type(8))) short bf16x8;
typedef __attribute__((ext_vector_type(4))) float f32x4;

__device__ __forceinline__ float bf2f_lo(uint32_t u) {
    union { uint32_t u; float f; } v; v.u = u << 16; return v.f;
}
__device__ __forceinline__ float bf2f_hi(uint32_t u) {
    union { uint32_t u; float f; } v; v.u = u & 0xffff0000u; return v.f;
}
__device__ __forceinline__ unsigned short f2bf(float f) {
    union { float f; uint32_t u; } v; v.f = f;
    return (unsigned short)((v.u + 0x7fffu + ((v.u >> 16) & 1u)) >> 16);
}
__device__ __forceinline__ float sigf(float x) { return 1.0f / (1.0f + __expf(-x)); }
__device__ __forceinline__ void gld_lds16(const void* g, void* l) {
    __builtin_amdgcn_global_load_lds(
        (__attribute__((address_space(1))) unsigned int*)g,
        (__attribute__((address_space(3))) unsigned int*)l, 16, 0, 0);
}

// ---------------------------------------------------------------------------
// ln_k: LayerNorm(inputs) fp32 -> bf16 ONLY.  8192 blocks x 16 rows.
// Round-4-verified mechanics: DMA-stage 16 KB tile, __syncthreads, compute.
// Isolated in its own dispatch so rocprof attributes its time separately.
// ---------------------------------------------------------------------------
__global__ __launch_bounds__(256) void ln_k(
    const float* __restrict__ in, const float* __restrict__ g_,
    const float* __restrict__ b_, unsigned short* __restrict__ xbf) {
    __shared__ __align__(16) float xs[16][256];
    int t = threadIdx.x, wave = t >> 6, lane = t & 63;
    size_t rb = (size_t)blockIdx.x * 16 + wave * 4;   // this wave's 4 rows
    const float* gsrc = in + rb * 256;
#pragma unroll
    for (int i = 0; i < 4; ++i)
        gld_lds16(gsrc + i * 256 + lane * 4, &xs[wave * 4 + i][0]);
    __syncthreads();

    float4 g4 = *(const float4*)(g_ + lane * 4);
    float4 b4 = *(const float4*)(b_ + lane * 4);
#pragma unroll
    for (int p = 0; p < 2; ++p) {   // two rows at a time for ILP
        float4 x0 = *(const float4*)&xs[wave * 4 + p * 2 + 0][lane * 4];
        float4 x1 = *(const float4*)&xs[wave * 4 + p * 2 + 1][lane * 4];
        float s0 = x0.x + x0.y + x0.z + x0.w;
        float q0 = x0.x * x0.x + x0.y * x0.y + x0.z * x0.z + x0.w * x0.w;
        float s1 = x1.x + x1.y + x1.z + x1.w;
        float q1 = x1.x * x1.x + x1.y * x1.y + x1.z * x1.z + x1.w * x1.w;
#pragma unroll
        for (int off = 32; off > 0; off >>= 1) {
            s0 += __shfl_xor(s0, off, 64);  q0 += __shfl_xor(q0, off, 64);
            s1 += __shfl_xor(s1, off, 64);  q1 += __shfl_xor(q1, off, 64);
        }
        float m0 = s0 * (1.0f / 256.0f);
        float r0 = rsqrtf(q0 * (1.0f / 256.0f) - m0 * m0 + 1e-3f);
        float m1 = s1 * (1.0f / 256.0f);
        float r1 = rsqrtf(q1 * (1.0f / 256.0f) - m1 * m1 + 1e-3f);
        uint2 o0, o1;
        o0.x = (uint32_t)f2bf((x0.x - m0) * r0 * g4.x + b4.x) |
               ((uint32_t)f2bf((x0.y - m0) * r0 * g4.y + b4.y) << 16);
        o0.y = (uint32_t)f2bf((x0.z - m0) * r0 * g4.z + b4.z) |
               ((uint32_t)f2bf((x0.w - m0) * r0 * g4.w + b4.w) << 16);
        o1.x = (uint32_t)f2bf((x1.x - m1) * r1 * g4.x + b4.x) |
               ((uint32_t)f2bf((x1.y - m1) * r1 * g4.y + b4.y) << 16);
        o1.y = (uint32_t)f2bf((x1.z - m1) * r1 * g4.z + b4.z) |
               ((uint32_t)f2bf((x1.w - m1) * r1 * g4.w + b4.w) << 16);
        *(uint2*)(xbf + (rb + p * 2 + 0) * 256 + lane * 4) = o0;
        *(uint2*)(xbf + (rb + p * 2 + 1) * 256 + lane * 4) = o1;
    }
}

// ---------------------------------------------------------------------------
// aux_k: weights cvt + biases + zero + q0 (q0 overlapped with weight cvt).
//   [0, 3328)     weight cvt fp32->bf16 (Wkv, Wg, W1b, W2b, Wqb) + biases
//   [3328, 3393)  zero upd/sums accumulators for iteration 0
//   [3393, 3425)  q0 = LN_slot(slots_in) @ Wq^T + bq   (one block per batch)
// ---------------------------------------------------------------------------
__global__ __launch_bounds__(256) void aux_k(
    const float* __restrict__ Wk, const float* __restrict__ Wv,
    const float* __restrict__ W_ih, const float* __restrict__ W_hh,
    const float* __restrict__ W1, const float* __restrict__ W2,
    const float* __restrict__ bk, const float* __restrict__ bv,
    const float* __restrict__ b_ih, const float* __restrict__ b_hh,
    unsigned short* __restrict__ Wkv, unsigned short* __restrict__ Wg,
    unsigned short* __restrict__ W1b, unsigned short* __restrict__ W2b,
    unsigned short* __restrict__ Wqb,
    float* __restrict__ bkv, float* __restrict__ bg,
    const float* __restrict__ slots_in, const float* __restrict__ g_slot,
    const float* __restrict__ b_slot, const float* __restrict__ Wq,
    const float* __restrict__ bq, unsigned short* __restrict__ qbuf,
    float* __restrict__ upd) {
    __shared__ __align__(16) unsigned short A1[8 * 264];
    int bid = blockIdx.x, t = threadIdx.x;
    int wave = t >> 6, lane = t & 63;

    if (bid < 3328) {
        int i = bid * 256 + t;
        if (i < 131072) {
            float v = (i < 65536) ? Wk[i] : Wv[i - 65536];
            Wkv[i] = f2bf(v);
        } else if (i < 524288) {
            int j = i - 131072;
            Wg[j] = f2bf(j < 196608 ? W_ih[j] : W_hh[j - 196608]);
        } else if (i < 655360) W1b[i - 524288] = f2bf(W1[i - 524288]);
        else if (i < 786432)   W2b[i - 655360] = f2bf(W2[i - 655360]);
        else                   Wqb[i - 786432] = f2bf(Wq[i - 786432]);
        if (i < 512)           bkv[i] = (i < 256 ? bk[i] : bv[i - 256]);
        else if (i < 2048)   { int j = i - 512; bg[j] = (j < 768 ? b_ih[j] : b_hh[j - 768]); }
        return;
    }
    if (bid < 3393) {
        // zero upd[65536] + sums[256] (contiguous)
        int i = (bid - 3328) * 1024 + t * 4;
        if (i < 65792) *(float4*)(upd + i) = make_float4(0.f, 0.f, 0.f, 0.f);
        return;
    }
    // ---- q0 segment: one block per batch ----
    int b = bid - 3393;
    {
        float4 g4 = *(const float4*)(g_slot + lane * 4);
        float4 b4 = *(const float4*)(b_slot + lane * 4);
#pragma unroll
        for (int rep = 0; rep < 2; ++rep) {
            int s = wave * 2 + rep;
            float4 x = *(const float4*)(slots_in + (size_t)b * 2048 + s * 256 + lane * 4);
            float sm = x.x + x.y + x.z + x.w;
            float sq = x.x * x.x + x.y * x.y + x.z * x.z + x.w * x.w;
#pragma unroll
            for (int off = 32; off > 0; off >>= 1) {
                sm += __shfl_xor(sm, off, 64);
                sq += __shfl_xor(sq, off, 64);
            }
            float mean = sm * (1.0f / 256.0f);
            float rstd = rsqrtf(sq * (1.0f / 256.0f) - mean * mean + 1e-3f);
            uint2 o;
            o.x = (uint32_t)f2bf((x.x - mean) * rstd * g4.x + b4.x) |
                  ((uint32_t)f2bf((x.y - mean) * rstd * g4.y + b4.y) << 16);
            o.y = (uint32_t)f2bf((x.z - mean) * rstd * g4.z + b4.z) |
                  ((uint32_t)f2bf((x.w - mean) * rstd * g4.w + b4.w) << 16);
            *(uint2*)&A1[s * 264 + lane * 4] = o;
        }
    }
    __syncthreads();
    {
        bf16x8 af[8];
#pragma unroll
        for (int ks = 0; ks < 8; ++ks)
            af[ks] = *(const bf16x8*)&A1[(lane & 15) * 264 + ks * 32 + (lane >> 4) * 8];
#pragma unroll
        for (int nt = 0; nt < 4; ++nt) {
            int n0 = (wave * 4 + nt) * 16;
            f32x4 a = {0.f, 0.f, 0.f, 0.f};
#pragma unroll
            for (int ks = 0; ks < 8; ++ks) {
                const float* wp = Wq + (size_t)(n0 + (lane & 15)) * 256 +
                                  ks * 32 + (lane >> 4) * 8;
                float4 wa = *(const float4*)wp;
                float4 wb = *(const float4*)(wp + 4);
                bf16x8 bfr;
                bfr[0] = (short)f2bf(wa.x); bfr[1] = (short)f2bf(wa.y);
                bfr[2] = (short)f2bf(wa.z); bfr[3] = (short)f2bf(wa.w);
                bfr[4] = (short)f2bf(wb.x); bfr[5] = (short)f2bf(wb.y);
                bfr[6] = (short)f2bf(wb.z); bfr[7] = (short)f2bf(wb.w);
                a = __builtin_amdgcn_mfma_f32_16x16x32_bf16(af[ks], bfr, a, 0, 0, 0);
            }
            int col = n0 + (lane & 15);
            float bs = bq[col];
#pragma unroll
            for (int r = 0; r < 4; ++r) {
                int row = (lane >> 4) * 4 + r;
                if (row < 8)
                    qbuf[((size_t)b * 8 + row) * 256 + col] = f2bf(a[r] + bs);
            }
        }
    }
}

// ---------------------------------------------------------------------------
// K/V GEMM: XCD swizzle; LDS swizzle via per-lane SOURCE address permutation
// in global_load_lds (global layout linear).  (unchanged)
// ---------------------------------------------------------------------------
__global__ __launch_bounds__(256) void gemm_kv(const unsigned short* __restrict__ X,
                                               const unsigned short* __restrict__ W,
                                               const float* __restrict__ bkv,
                                               unsigned short* __restrict__ Ko,
                                               unsigned short* __restrict__ Vo) {
    __shared__ __align__(16) unsigned short As[128 * 64];
    __shared__ __align__(16) unsigned short Bs[128 * 64];
    int t = threadIdx.x, wave = t >> 6, lane = t & 63;
    int wr = wave >> 1, wc = wave & 1;
    int bid = blockIdx.x;
    int m0 = (((bid >> 5) << 3) | (bid & 7)) * 128;
    int j0 = ((bid >> 3) & 3) * 128;

    int rsub = lane >> 3;                 // row within the 8-row staging group
    int sblk = (lane & 7) ^ rsub;         // swizzled source k-block

    f32x4 acc[4][4];
#pragma unroll
    for (int i = 0; i < 4; ++i)
#pragma unroll
        for (int j = 0; j < 4; ++j)
#pragma unroll
            for (int r = 0; r < 4; ++r) acc[i][j][r] = 0.f;

    for (int kb = 0; kb < 4; ++kb) {
        int k0 = kb * 64;
#pragma unroll
        for (int i = 0; i < 4; ++i) {
            int rbase = wave * 32 + i * 8;   // multiple of 8 -> (row&7) = rsub
            gld_lds16(X + (size_t)(m0 + rbase + rsub) * 256 + k0 + sblk * 8,
                      &As[rbase * 64]);
            gld_lds16(W + (size_t)(j0 + rbase + rsub) * 256 + k0 + sblk * 8,
                      &Bs[rbase * 64]);
        }
        __syncthreads();
#pragma unroll
        for (int kk = 0; kk < 64; kk += 32) {
            int koff = kk + (lane >> 4) * 8;
            int cl = koff >> 3;
            bf16x8 af[4], bf[4];
#pragma unroll
            for (int ti = 0; ti < 4; ++ti) {
                int r = wr * 64 + ti * 16 + (lane & 15);
                af[ti] = *(const bf16x8*)&As[r * 64 + ((cl ^ (r & 7)) << 3)];
            }
#pragma unroll
            for (int tj = 0; tj < 4; ++tj) {
                int c = wc * 64 + tj * 16 + (lane & 15);
                bf[tj] = *(const bf16x8*)&Bs[c * 64 + ((cl ^ (c & 7)) << 3)];
            }
#pragma unroll
            for (int ti = 0; ti < 4; ++ti)
#pragma unroll
                for (int tj = 0; tj < 4; ++tj)
                    acc[ti][tj] = __builtin_amdgcn_mfma_f32_16x16x32_bf16(
                        af[ti], bf[tj], acc[ti][tj], 0, 0, 0);
        }
        __syncthreads();
    }
    bool isK = (j0 < 256);
    unsigned short* base = isK ? Ko : Vo;
#pragma unroll
    for (int ti = 0; ti < 4; ++ti)
#pragma unroll
        for (int tj = 0; tj < 4; ++tj) {
            int col = j0 + wc * 64 + tj * 16 + (lane & 15);
            float bias = bkv[col];
            int outc = col & 255;
#pragma unroll
            for (int r = 0; r < 4; ++r) {
                int row = m0 + wr * 64 + ti * 16 + (lane >> 4) * 4 + r;
                base[(size_t)row * 256 + outc] = f2bf(acc[ti][tj][r] + bias);
            }
        }
}

// ---------------------------------------------------------------------------
// Fused attention: chunk = 256 n, grid (32,16).  (unchanged)
// ---------------------------------------------------------------------------
__global__ __launch_bounds__(256) void attn_fused(
    const unsigned short* __restrict__ qb, const unsigned short* __restrict__ K,
    const unsigned short* __restrict__ V,
    float* __restrict__ upd, float* __restrict__ sums) {
    __shared__ __align__(16) unsigned short qs[8 * 264];
    __shared__ __align__(16) float atf[8 * 256];
    __shared__ __align__(16) float pr[4][8 * 256];
    __shared__ float ssum[8];
    int b = blockIdx.x, ch = blockIdx.y, t = threadIdx.x;
    int wave = t >> 6, lane = t & 63;

    *(uint4*)&qs[(t >> 5) * 264 + (t & 31) * 8] = ((const uint4*)(qb + (size_t)b * 2048))[t];
    if (t < 8) ssum[t] = 0.f;
    __syncthreads();

    // ---- QK^T via MFMA: dots[s(8, pad to 16)][n = 256-chunk] ----
    {
        bf16x8 af[8];
#pragma unroll
        for (int ks = 0; ks < 8; ++ks)
            af[ks] = *(const bf16x8*)&qs[(lane & 7) * 264 + ks * 32 + (lane >> 4) * 8];
        const unsigned short* kb_ = K + ((size_t)b * 4096 + ch * 256) * 256;
#pragma unroll
        for (int nt = 0; nt < 4; ++nt) {
            int n0 = (wave * 4 + nt) * 16;
            const unsigned short* kp = kb_ + (size_t)(n0 + (lane & 15)) * 256 + (lane >> 4) * 8;
            f32x4 a = {0.f, 0.f, 0.f, 0.f};
#pragma unroll
            for (int ks = 0; ks < 8; ++ks) {
                bf16x8 bfr = *(const bf16x8*)(kp + ks * 32);
                a = __builtin_amdgcn_mfma_f32_16x16x32_bf16(af[ks], bfr, a, 0, 0, 0);
            }
            if (lane < 32) {
                int n = n0 + (lane & 15);
                int s0 = (lane >> 4) * 4;
#pragma unroll
                for (int r = 0; r < 4; ++r)
                    atf[(s0 + r) * 256 + n] = a[r] * 0.0625f;
            }
        }
    }
    __syncthreads();

    // ---- softmax over slots + per-slot sums ----
    {
        int n = t;
        float v[8];
#pragma unroll
        for (int s = 0; s < 8; ++s) v[s] = atf[s * 256 + n];
        float m = v[0];
#pragma unroll
        for (int s = 1; s < 8; ++s) m = fmaxf(m, v[s]);
        float sum = 0.f;
#pragma unroll
        for (int s = 0; s < 8; ++s) { v[s] = __expf(v[s] - m); sum += v[s]; }
        float inv = 1.0f / sum;
        float ts[8];
#pragma unroll
        for (int s = 0; s < 8; ++s) {
            float a = v[s] * inv + 1e-8f;
            atf[s * 256 + n] = a;
            ts[s] = a;
        }
#pragma unroll
        for (int s = 0; s < 8; ++s) {
#pragma unroll
            for (int off = 32; off > 0; off >>= 1)
                ts[s] += __shfl_xor(ts[s], off, 64);
        }
        if (lane == 0) {
#pragma unroll
            for (int s = 0; s < 8; ++s) atomicAdd(&ssum[s], ts[s]);
        }
    }
    __syncthreads();
    if (t < 8) atomicAdd(&sums[b * 8 + t], ssum[t]);

    // ---- PV: register double-buffered V loads ----
    float ua[8][4];
#pragma unroll
    for (int s = 0; s < 8; ++s)
#pragma unroll
        for (int k = 0; k < 4; ++k) ua[s][k] = 0.f;
    const unsigned short* vb = V + ((size_t)b * 4096 + ch * 256 + wave * 64) * 256 + lane * 4;
    uint2 vv[4], vn[4];
#pragma unroll
    for (int kk = 0; kk < 4; ++kk) vv[kk] = *(const uint2*)(vb + (size_t)kk * 256);
    for (int g = 0; g < 16; ++g) {
        if (g < 15) {
            const unsigned short* nrow = vb + (size_t)(g + 1) * 1024;
#pragma unroll
            for (int kk = 0; kk < 4; ++kk) vn[kk] = *(const uint2*)(nrow + (size_t)kk * 256);
        }
        int nl = wave * 64 + g * 4;
        float4 a4[8];
#pragma unroll
        for (int s = 0; s < 8; ++s) a4[s] = *(const float4*)&atf[s * 256 + nl];
#define UPD_STEP(kk, comp)                                                     \
        {                                                                      \
            float v0 = bf2f_lo(vv[kk].x), v1 = bf2f_hi(vv[kk].x);              \
            float v2 = bf2f_lo(vv[kk].y), v3 = bf2f_hi(vv[kk].y);              \
            _Pragma("unroll")                                                  \
            for (int s = 0; s < 8; ++s) {                                      \
                float a = a4[s].comp;                                          \
                ua[s][0] += a * v0; ua[s][1] += a * v1;                        \
                ua[s][2] += a * v2; ua[s][3] += a * v3;                        \
            }                                                                  \
        }
        UPD_STEP(0, x) UPD_STEP(1, y) UPD_STEP(2, z) UPD_STEP(3, w)
#undef UPD_STEP
#pragma unroll
        for (int kk = 0; kk < 4; ++kk) vv[kk] = vn[kk];
    }
#pragma unroll
    for (int s = 0; s < 8; ++s)
        *(float4*)&pr[wave][s * 256 + lane * 4] = *(float4*)ua[s];
    __syncthreads();
    for (int i = t; i < 2048; i += 256) {
        float vsum = pr[0][i] + pr[1][i] + pr[2][i] + pr[3][i];
        atomicAdd(&upd[(size_t)b * 2048 + i], vsum);
    }
}

// ---------------------------------------------------------------------------
// Slot tail: 512 threads (8 waves).  (unchanged)
// ---------------------------------------------------------------------------
__global__ __launch_bounds__(512, 1) void slot_tail(
    const float* __restrict__ upd, const float* __restrict__ sums,
    float* __restrict__ upd_w, float* __restrict__ sums_w,
    const float* __restrict__ cur,
    const unsigned short* __restrict__ Wg, const float* __restrict__ bg,
    const float* __restrict__ g_mlp, const float* __restrict__ b_mlp,
    const unsigned short* __restrict__ W1b, const float* __restrict__ b1,
    const unsigned short* __restrict__ W2b, const float* __restrict__ b2,
    const float* __restrict__ g_slot, const float* __restrict__ b_slot,
    const unsigned short* __restrict__ Wqb, const float* __restrict__ bq,
    float* __restrict__ slots_out, unsigned short* __restrict__ qbuf,
    int do_q) {
    __shared__ float gts[8 * 1536];
    __shared__ float hn[2048];
    __shared__ float sn[2048];
    __shared__ __align__(16) unsigned short A1u[8 * 264];
    __shared__ __align__(16) unsigned short A1h[8 * 264];
    __shared__ __align__(16) unsigned short A1[8 * 264];
    __shared__ __align__(16) unsigned short A2[8 * 520];
    __shared__ float ssum8[8];
    int b = blockIdx.x, t = threadIdx.x;
    int wave = t >> 6, lane = t & 63;

    if (t < 8) ssum8[t] = sums[b * 8 + t];
    __syncthreads();
    for (int idx = t; idx < 2048; idx += 512) {
        int row = idx >> 8, d = idx & 255;
        A1u[row * 264 + d] = f2bf(upd[(size_t)b * 2048 + idx] / ssum8[row]);
        A1h[row * 264 + d] = f2bf(cur[(size_t)b * 2048 + idx]);
    }
    __syncthreads();
    // zero accumulators for the next attn launch (deterministic, per-b slice)
    for (int idx = t; idx < 2048; idx += 512) upd_w[(size_t)b * 2048 + idx] = 0.f;
    if (t < 8) sums_w[b * 8 + t] = 0.f;

    // ---- gates GEMM: 96 col-tiles, waves 0-3 -> u@W_ih, 4-7 -> h@W_hh ----
    {
        const unsigned short* Af = (wave < 4) ? A1u : A1h;
        bf16x8 af[8];
#pragma unroll
        for (int ks = 0; ks < 8; ++ks)
            af[ks] = *(const bf16x8*)&Af[(lane & 15) * 264 + ks * 32 + (lane >> 4) * 8];
#pragma unroll
        for (int nt = 0; nt < 12; ++nt) {
            int n0 = wave * 192 + nt * 16;
            f32x4 a = {0.f, 0.f, 0.f, 0.f};
#pragma unroll
            for (int ks = 0; ks < 8; ++ks) {
                bf16x8 bfr = *(const bf16x8*)(Wg + (size_t)(n0 + (lane & 15)) * 256 +
                                              ks * 32 + (lane >> 4) * 8);
                a = __builtin_amdgcn_mfma_f32_16x16x32_bf16(af[ks], bfr, a, 0, 0, 0);
            }
            int col = n0 + (lane & 15);
            float bs = bg[col];
#pragma unroll
            for (int r = 0; r < 4; ++r) {
                int row = (lane >> 4) * 4 + r;
                if (row < 8) gts[row * 1536 + col] = a[r] + bs;
            }
        }
    }
    __syncthreads();

    // ---- GRU combine ----
#pragma unroll
    for (int p = 0; p < 4; ++p) {
        int idx = p * 512 + t;
        int s = idx >> 8, j = idx & 255;
        const float* gr = &gts[s * 1536];
        float r  = sigf(gr[j] + gr[768 + j]);
        float z  = sigf(gr[256 + j] + gr[1024 + j]);
        float nn = tanhf(gr[512 + j] + r * gr[1280 + j]);
        float h  = cur[(size_t)b * 2048 + idx];
        hn[idx] = (1.0f - z) * nn + z * h;
    }
    __syncthreads();

    // ---- LN(mlp) -> A1, one row per wave ----
    {
        float4 g4 = *(const float4*)(g_mlp + lane * 4);
        float4 b4 = *(const float4*)(b_mlp + lane * 4);
        int s = wave;
        float4 x = *(const float4*)&hn[s * 256 + lane * 4];
        float sm = x.x + x.y + x.z + x.w;
        float sq = x.x * x.x + x.y * x.y + x.z * x.z + x.w * x.w;
#pragma unroll
        for (int off = 32; off > 0; off >>= 1) {
            sm += __shfl_xor(sm, off, 64);
            sq += __shfl_xor(sq, off, 64);
        }
        float mean = sm * (1.0f / 256.0f);
        float rstd = rsqrtf(sq * (1.0f / 256.0f) - mean * mean + 1e-3f);
        uint2 o;
        o.x = (uint32_t)f2bf((x.x - mean) * rstd * g4.x + b4.x) |
              ((uint32_t)f2bf((x.y - mean) * rstd * g4.y + b4.y) << 16);
        o.y = (uint32_t)f2bf((x.z - mean) * rstd * g4.z + b4.z) |
              ((uint32_t)f2bf((x.w - mean) * rstd * g4.w + b4.w) << 16);
        *(uint2*)&A1[s * 264 + lane * 4] = o;
    }
    __syncthreads();

    // ---- MLP1: A2 = relu(A1 @ W1^T + b1), 32 tiles / 8 waves ----
    {
        bf16x8 af[8];
#pragma unroll
        for (int ks = 0; ks < 8; ++ks)
            af[ks] = *(const bf16x8*)&A1[(lane & 15) * 264 + ks * 32 + (lane >> 4) * 8];
#pragma unroll
        for (int nt = 0; nt < 4; ++nt) {
            int n0 = (wave * 4 + nt) * 16;
            f32x4 a = {0.f, 0.f, 0.f, 0.f};
#pragma unroll
            for (int ks = 0; ks < 8; ++ks) {
                bf16x8 bfr = *(const bf16x8*)(W1b + (size_t)(n0 + (lane & 15)) * 256 +
                                              ks * 32 + (lane >> 4) * 8);
                a = __builtin_amdgcn_mfma_f32_16x16x32_bf16(af[ks], bfr, a, 0, 0, 0);
            }
            int col = n0 + (lane & 15);
            float bs = b1[col];
#pragma unroll
            for (int r = 0; r < 4; ++r) {
                int row = (lane >> 4) * 4 + r;
                if (row < 8) A2[row * 520 + col] = f2bf(fmaxf(a[r] + bs, 0.f));
            }
        }
    }
    __syncthreads();

    // ---- MLP2: sn = A2 @ W2^T + b2 + hn, 16 tiles / 8 waves ----
    {
        bf16x8 af[16];
#pragma unroll
        for (int ks = 0; ks < 16; ++ks)
            af[ks] = *(const bf16x8*)&A2[(lane & 15) * 520 + ks * 32 + (lane >> 4) * 8];
#pragma unroll
        for (int nt = 0; nt < 2; ++nt) {
            int n0 = (wave * 2 + nt) * 16;
            f32x4 a = {0.f, 0.f, 0.f, 0.f};
#pragma unroll
            for (int ks = 0; ks < 16; ++ks) {
                bf16x8 bfr = *(const bf16x8*)(W2b + (size_t)(n0 + (lane & 15)) * 512 +
                                              ks * 32 + (lane >> 4) * 8);
                a = __builtin_amdgcn_mfma_f32_16x16x32_bf16(af[ks], bfr, a, 0, 0, 0);
            }
            int col = n0 + (lane & 15);
            float bs = b2[col];
#pragma unroll
            for (int r = 0; r < 4; ++r) {
                int row = (lane >> 4) * 4 + r;
                if (row < 8) {
                    float v = a[r] + bs + hn[row * 256 + col];
                    sn[row * 256 + col] = v;
                    slots_out[((size_t)b * 8 + row) * 256 + col] = v;
                }
            }
        }
    }
    if (!do_q) return;
    __syncthreads();

    // ---- LN(slot) on sn -> A1 ----
    {
        float4 g4 = *(const float4*)(g_slot + lane * 4);
        float4 b4 = *(const float4*)(b_slot + lane * 4);
        int s = wave;
        float4 x = *(const float4*)&sn[s * 256 + lane * 4];
        float sm = x.x + x.y + x.z + x.w;
        float sq = x.x * x.x + x.y * x.y + x.z * x.z + x.w * x.w;
#pragma unroll
        for (int off = 32; off > 0; off >>= 1) {
            sm += __shfl_xor(sm, off, 64);
            sq += __shfl_xor(sq, off, 64);
        }
        float mean = sm * (1.0f / 256.0f);
        float rstd = rsqrtf(sq * (1.0f / 256.0f) - mean * mean + 1e-3f);
        uint2 o;
        o.x = (uint32_t)f2bf((x.x - mean) * rstd * g4.x + b4.x) |
              ((uint32_t)f2bf((x.y - mean) * rstd * g4.y + b4.y) << 16);
        o.y = (uint32_t)f2bf((x.z - mean) * rstd * g4.z + b4.z) |
              ((uint32_t)f2bf((x.w - mean) * rstd * g4.w + b4.w) << 16);
        *(uint2*)&A1[s * 264 + lane * 4] = o;
    }
    __syncthreads();

    // ---- q = A1 @ Wq^T + bq, 16 tiles / 8 waves ----
    {
        bf16x8 af[8];
#pragma unroll
        for (int ks = 0; ks < 8; ++ks)
            af[ks] = *(const bf16x8*)&A1[(lane & 15) * 264 + ks * 32 + (lane >> 4) * 8];
#pragma unroll
        for (int nt = 0; nt < 2; ++nt) {
            int n0 = (wave * 2 + nt) * 16;
            f32x4 a = {0.f, 0.f, 0.f, 0.f};
#pragma unroll
            for (int ks = 0; ks < 8; ++ks) {
                bf16x8 bfr = *(const bf16x8*)(Wqb + (size_t)(n0 + (lane & 15)) * 256 +
                                              ks * 32 + (lane >> 4) * 8);
                a = __builtin_amdgcn_mfma_f32_16x16x32_bf16(af[ks], bfr, a, 0, 0, 0);
            }
            int col = n0 + (lane & 15);
            float bs = bq[col];
#pragma unroll
            for (int r = 0; r < 4; ++r) {
                int row = (lane >> 4) * 4 + r;
                if (row < 8)
                    qbuf[((size_t)b * 8 + row) * 256 + col] = f2bf(a[r] + bs);
            }
        }
    }
}

// ---------------------------------------------------------------------------
extern "C" void kernel_launch(void* const* d_in, const int* in_sizes, int n_in,
                              void* d_out, int out_size, void* d_ws, size_t ws_size,
                              hipStream_t stream) {
    const float* inputs    = (const float*)d_in[0];
    const float* slots_in  = (const float*)d_in[1];
    const float* ln_in_g   = (const float*)d_in[3];
    const float* ln_in_b   = (const float*)d_in[4];
    const float* ln_slot_g = (const float*)d_in[5];
    const float* ln_slot_b = (const float*)d_in[6];
    const float* ln_mlp_g  = (const float*)d_in[7];
    const float* ln_mlp_b  = (const float*)d_in[8];
    const float* Wq   = (const float*)d_in[9];
    const float* bq   = (const float*)d_in[10];
    const float* Wk   = (const float*)d_in[11];
    const float* bk   = (const float*)d_in[12];
    const float* Wv   = (const float*)d_in[13];
    const float* bv   = (const float*)d_in[14];
    const float* W_ih = (const float*)d_in[15];
    const float* b_ih = (const float*)d_in[16];
    const float* W_hh = (const float*)d_in[17];
    const float* b_hh = (const float*)d_in[18];
    const float* W1   = (const float*)d_in[19];
    const float* b1   = (const float*)d_in[20];
    const float* W2   = (const float*)d_in[21];
    const float* b2   = (const float*)d_in[22];

    char* p = (char*)d_ws;
    size_t off = 0;
    auto take = [&](size_t bytes) -> char* {
        char* r = p + off;
        off += (bytes + 255) & ~(size_t)255;
        return r;
    };
    unsigned short* xbf  = (unsigned short*)take((size_t)131072 * 256 * 2);
    unsigned short* Kb   = (unsigned short*)take((size_t)131072 * 256 * 2);
    unsigned short* Vb   = (unsigned short*)take((size_t)131072 * 256 * 2);
    unsigned short* Wkv  = (unsigned short*)take(131072 * 2);
    unsigned short* Wg   = (unsigned short*)take(393216 * 2);
    unsigned short* W1b  = (unsigned short*)take(131072 * 2);
    unsigned short* W2b  = (unsigned short*)take(131072 * 2);
    unsigned short* Wqb  = (unsigned short*)take(65536 * 2);
    float* bkv   = (float*)take(512 * 4);
    float* bg    = (float*)take(1536 * 4);
    unsigned short* qbuf = (unsigned short*)take(65536 * 2);
    float* upd   = (float*)take((65536 + 256) * 4);   // upd + sums contiguous
    float* sums  = upd + 65536;
    float* sA    = (float*)take(65536 * 4);
    float* sB    = (float*)take(65536 * 4);

    aux_k<<<3425, 256, 0, stream>>>(Wk, Wv, W_ih, W_hh, W1, W2,
                                    bk, bv, b_ih, b_hh,
                                    Wkv, Wg, W1b, W2b, Wqb, bkv, bg,
                                    slots_in, ln_slot_g, ln_slot_b, Wq, bq, qbuf,
                                    upd);
    ln_k<<<8192, 256, 0, stream>>>(inputs, ln_in_g, ln_in_b, xbf);
    gemm_kv<<<4096, 256, 0, stream>>>(xbf, Wkv, bkv, Kb, Vb);

    const float* cur = slots_in;
    float* nxt[3] = {sA, sB, (float*)d_out};
    for (int it = 0; it < 3; ++it) {
        attn_fused<<<dim3(32, 16), 256, 0, stream>>>(qbuf, Kb, Vb, upd, sums);
        slot_tail<<<32, 512, 0, stream>>>(upd, sums, upd, sums, cur, Wg, bg,
                                          ln_mlp_g, ln_mlp_b, W1b, b1, W2b, b2,
                                          ln_slot_g, ln_slot_b, Wqb, bq,
                                          nxt[it], qbuf, it < 2 ? 1 : 0);
        cur = nxt[it];
    }
    (void)in_sizes; (void)n_in; (void)out_size; (void)ws_size;
}

// Round 8
// 515.869 us; speedup vs baseline: 1.0432x; 1.0432x over previous
//
#include <hip/hip_runtime.h>
#include <stdint.h>

// B=32, N=4096, D=256, S=8, H_MLP=512, 3 iterations.

typedef __attribute__((ext_vector_type(8))) short bf16x8;
typedef __attribute__((ext_vector_type(4))) float f32x4;

__device__ __forceinline__ float bf2f_lo(uint32_t u) {
    union { uint32_t u; float f; } v; v.u = u << 16; return v.f;
}
__device__ __forceinline__ float bf2f_hi(uint32_t u) {
    union { uint32_t u; float f; } v; v.u = u & 0xffff0000u; return v.f;
}
__device__ __forceinline__ unsigned short f2bf(float f) {
    union { float f; uint32_t u; } v; v.f = f;
    return (unsigned short)((v.u + 0x7fffu + ((v.u >> 16) & 1u)) >> 16);
}
__device__ __forceinline__ float sigf(float x) { return 1.0f / (1.0f + __expf(-x)); }
__device__ __forceinline__ void gld_lds16(const void* g, void* l) {
    __builtin_amdgcn_global_load_lds(
        (__attribute__((address_space(1))) unsigned int*)g,
        (__attribute__((address_space(3))) unsigned int*)l, 16, 0, 0);
}

// ---------------------------------------------------------------------------
// prep_k grid segments (latency-bound q0 FIRST so it hides under LN stream):
//   [0, 32)         q0 = LN_slot(slots_in) @ Wq^T + bq  (one block per batch)
//   [32, 3360)      weight cvt fp32->bf16 (Wkv, Wg, W1b, W2b, Wqb) + biases
//   [3360, 11552)   LN(inputs): 16 rows/block, DMA-staged (round-4 mechanics)
// ---------------------------------------------------------------------------
__global__ __launch_bounds__(256) void prep_k(
    const float* __restrict__ in, const float* __restrict__ ln_in_g,
    const float* __restrict__ ln_in_b, unsigned short* __restrict__ xbf,
    const float* __restrict__ Wk, const float* __restrict__ Wv,
    const float* __restrict__ W_ih, const float* __restrict__ W_hh,
    const float* __restrict__ W1, const float* __restrict__ W2,
    const float* __restrict__ bk, const float* __restrict__ bv,
    const float* __restrict__ b_ih, const float* __restrict__ b_hh,
    unsigned short* __restrict__ Wkv, unsigned short* __restrict__ Wg,
    unsigned short* __restrict__ W1b, unsigned short* __restrict__ W2b,
    unsigned short* __restrict__ Wqb,
    float* __restrict__ bkv, float* __restrict__ bg,
    const float* __restrict__ slots_in, const float* __restrict__ g_slot,
    const float* __restrict__ b_slot, const float* __restrict__ Wq,
    const float* __restrict__ bq, unsigned short* __restrict__ qbuf) {
    // 16 KB shared, overlaid: LN staging [16][256] f32  /  q0's A1 [8][264] bf16
    __shared__ __align__(16) char smem[16384];
    int bid = blockIdx.x, t = threadIdx.x;
    int wave = t >> 6, lane = t & 63;

    if (bid >= 3360) {
        // ---- LayerNorm inputs: 16 rows/block, DMA-staged ----
        float (*xs)[256] = (float(*)[256])smem;
        size_t rb = (size_t)(bid - 3360) * 16 + wave * 4;   // this wave's 4 rows
        const float* gsrc = in + rb * 256;
#pragma unroll
        for (int i = 0; i < 4; ++i)
            gld_lds16(gsrc + i * 256 + lane * 4, &xs[wave * 4 + i][0]);
        __syncthreads();

        float4 g4 = *(const float4*)(ln_in_g + lane * 4);
        float4 b4 = *(const float4*)(ln_in_b + lane * 4);
#pragma unroll
        for (int p = 0; p < 2; ++p) {   // two rows at a time for ILP
            float4 x0 = *(const float4*)&xs[wave * 4 + p * 2 + 0][lane * 4];
            float4 x1 = *(const float4*)&xs[wave * 4 + p * 2 + 1][lane * 4];
            float s0 = x0.x + x0.y + x0.z + x0.w;
            float q0 = x0.x * x0.x + x0.y * x0.y + x0.z * x0.z + x0.w * x0.w;
            float s1 = x1.x + x1.y + x1.z + x1.w;
            float q1 = x1.x * x1.x + x1.y * x1.y + x1.z * x1.z + x1.w * x1.w;
#pragma unroll
            for (int off = 32; off > 0; off >>= 1) {
                s0 += __shfl_xor(s0, off, 64);  q0 += __shfl_xor(q0, off, 64);
                s1 += __shfl_xor(s1, off, 64);  q1 += __shfl_xor(q1, off, 64);
            }
            float m0 = s0 * (1.0f / 256.0f);
            float r0 = rsqrtf(q0 * (1.0f / 256.0f) - m0 * m0 + 1e-3f);
            float m1 = s1 * (1.0f / 256.0f);
            float r1 = rsqrtf(q1 * (1.0f / 256.0f) - m1 * m1 + 1e-3f);
            uint2 o0, o1;
            o0.x = (uint32_t)f2bf((x0.x - m0) * r0 * g4.x + b4.x) |
                   ((uint32_t)f2bf((x0.y - m0) * r0 * g4.y + b4.y) << 16);
            o0.y = (uint32_t)f2bf((x0.z - m0) * r0 * g4.z + b4.z) |
                   ((uint32_t)f2bf((x0.w - m0) * r0 * g4.w + b4.w) << 16);
            o1.x = (uint32_t)f2bf((x1.x - m1) * r1 * g4.x + b4.x) |
                   ((uint32_t)f2bf((x1.y - m1) * r1 * g4.y + b4.y) << 16);
            o1.y = (uint32_t)f2bf((x1.z - m1) * r1 * g4.z + b4.z) |
                   ((uint32_t)f2bf((x1.w - m1) * r1 * g4.w + b4.w) << 16);
            *(uint2*)(xbf + (rb + p * 2 + 0) * 256 + lane * 4) = o0;
            *(uint2*)(xbf + (rb + p * 2 + 1) * 256 + lane * 4) = o1;
        }
        return;
    }
    if (bid >= 32) {
        int i = (bid - 32) * 256 + t;
        if (i < 131072) {
            float v = (i < 65536) ? Wk[i] : Wv[i - 65536];
            Wkv[i] = f2bf(v);
        } else if (i < 524288) {
            int j = i - 131072;
            Wg[j] = f2bf(j < 196608 ? W_ih[j] : W_hh[j - 196608]);
        } else if (i < 655360) W1b[i - 524288] = f2bf(W1[i - 524288]);
        else if (i < 786432)   W2b[i - 655360] = f2bf(W2[i - 655360]);
        else                   Wqb[i - 786432] = f2bf(Wq[i - 786432]);
        if (i < 512)           bkv[i] = (i < 256 ? bk[i] : bv[i - 256]);
        else if (i < 2048)   { int j = i - 512; bg[j] = (j < 768 ? b_ih[j] : b_hh[j - 768]); }
        return;
    }
    // ---- q0 segment: one block per batch (dispatched first, hides in stream)
    int b = bid;
    unsigned short* A1 = (unsigned short*)smem;    // [8][264]
    {
        float4 g4 = *(const float4*)(g_slot + lane * 4);
        float4 b4 = *(const float4*)(b_slot + lane * 4);
#pragma unroll
        for (int rep = 0; rep < 2; ++rep) {
            int s = wave * 2 + rep;
            float4 x = *(const float4*)(slots_in + (size_t)b * 2048 + s * 256 + lane * 4);
            float sm = x.x + x.y + x.z + x.w;
            float sq = x.x * x.x + x.y * x.y + x.z * x.z + x.w * x.w;
#pragma unroll
            for (int off = 32; off > 0; off >>= 1) {
                sm += __shfl_xor(sm, off, 64);
                sq += __shfl_xor(sq, off, 64);
            }
            float mean = sm * (1.0f / 256.0f);
            float rstd = rsqrtf(sq * (1.0f / 256.0f) - mean * mean + 1e-3f);
            uint2 o;
            o.x = (uint32_t)f2bf((x.x - mean) * rstd * g4.x + b4.x) |
                  ((uint32_t)f2bf((x.y - mean) * rstd * g4.y + b4.y) << 16);
            o.y = (uint32_t)f2bf((x.z - mean) * rstd * g4.z + b4.z) |
                  ((uint32_t)f2bf((x.w - mean) * rstd * g4.w + b4.w) << 16);
            *(uint2*)&A1[s * 264 + lane * 4] = o;
        }
    }
    __syncthreads();
    {
        bf16x8 af[8];
#pragma unroll
        for (int ks = 0; ks < 8; ++ks)
            af[ks] = *(const bf16x8*)&A1[(lane & 15) * 264 + ks * 32 + (lane >> 4) * 8];
#pragma unroll
        for (int nt = 0; nt < 4; ++nt) {
            int n0 = (wave * 4 + nt) * 16;
            f32x4 a = {0.f, 0.f, 0.f, 0.f};
#pragma unroll
            for (int ks = 0; ks < 8; ++ks) {
                const float* wp = Wq + (size_t)(n0 + (lane & 15)) * 256 +
                                  ks * 32 + (lane >> 4) * 8;
                float4 wa = *(const float4*)wp;
                float4 wb = *(const float4*)(wp + 4);
                bf16x8 bfr;
                bfr[0] = (short)f2bf(wa.x); bfr[1] = (short)f2bf(wa.y);
                bfr[2] = (short)f2bf(wa.z); bfr[3] = (short)f2bf(wa.w);
                bfr[4] = (short)f2bf(wb.x); bfr[5] = (short)f2bf(wb.y);
                bfr[6] = (short)f2bf(wb.z); bfr[7] = (short)f2bf(wb.w);
                a = __builtin_amdgcn_mfma_f32_16x16x32_bf16(af[ks], bfr, a, 0, 0, 0);
            }
            int col = n0 + (lane & 15);
            float bs = bq[col];
#pragma unroll
            for (int r = 0; r < 4; ++r) {
                int row = (lane >> 4) * 4 + r;
                if (row < 8)
                    qbuf[((size_t)b * 8 + row) * 256 + col] = f2bf(a[r] + bs);
            }
        }
    }
}

// ---------------------------------------------------------------------------
// K/V GEMM: XCD swizzle; LDS swizzle via per-lane SOURCE address permutation
// in global_load_lds (global layout linear).  (unchanged)
// ---------------------------------------------------------------------------
__global__ __launch_bounds__(256) void gemm_kv(const unsigned short* __restrict__ X,
                                               const unsigned short* __restrict__ W,
                                               const float* __restrict__ bkv,
                                               unsigned short* __restrict__ Ko,
                                               unsigned short* __restrict__ Vo) {
    __shared__ __align__(16) unsigned short As[128 * 64];
    __shared__ __align__(16) unsigned short Bs[128 * 64];
    int t = threadIdx.x, wave = t >> 6, lane = t & 63;
    int wr = wave >> 1, wc = wave & 1;
    int bid = blockIdx.x;
    int m0 = (((bid >> 5) << 3) | (bid & 7)) * 128;
    int j0 = ((bid >> 3) & 3) * 128;

    int rsub = lane >> 3;                 // row within the 8-row staging group
    int sblk = (lane & 7) ^ rsub;         // swizzled source k-block

    f32x4 acc[4][4];
#pragma unroll
    for (int i = 0; i < 4; ++i)
#pragma unroll
        for (int j = 0; j < 4; ++j)
#pragma unroll
            for (int r = 0; r < 4; ++r) acc[i][j][r] = 0.f;

    for (int kb = 0; kb < 4; ++kb) {
        int k0 = kb * 64;
#pragma unroll
        for (int i = 0; i < 4; ++i) {
            int rbase = wave * 32 + i * 8;   // multiple of 8 -> (row&7) = rsub
            gld_lds16(X + (size_t)(m0 + rbase + rsub) * 256 + k0 + sblk * 8,
                      &As[rbase * 64]);
            gld_lds16(W + (size_t)(j0 + rbase + rsub) * 256 + k0 + sblk * 8,
                      &Bs[rbase * 64]);
        }
        __syncthreads();
#pragma unroll
        for (int kk = 0; kk < 64; kk += 32) {
            int koff = kk + (lane >> 4) * 8;
            int cl = koff >> 3;
            bf16x8 af[4], bf[4];
#pragma unroll
            for (int ti = 0; ti < 4; ++ti) {
                int r = wr * 64 + ti * 16 + (lane & 15);
                af[ti] = *(const bf16x8*)&As[r * 64 + ((cl ^ (r & 7)) << 3)];
            }
#pragma unroll
            for (int tj = 0; tj < 4; ++tj) {
                int c = wc * 64 + tj * 16 + (lane & 15);
                bf[tj] = *(const bf16x8*)&Bs[c * 64 + ((cl ^ (c & 7)) << 3)];
            }
#pragma unroll
            for (int ti = 0; ti < 4; ++ti)
#pragma unroll
                for (int tj = 0; tj < 4; ++tj)
                    acc[ti][tj] = __builtin_amdgcn_mfma_f32_16x16x32_bf16(
                        af[ti], bf[tj], acc[ti][tj], 0, 0, 0);
        }
        __syncthreads();
    }
    bool isK = (j0 < 256);
    unsigned short* base = isK ? Ko : Vo;
#pragma unroll
    for (int ti = 0; ti < 4; ++ti)
#pragma unroll
        for (int tj = 0; tj < 4; ++tj) {
            int col = j0 + wc * 64 + tj * 16 + (lane & 15);
            float bias = bkv[col];
            int outc = col & 255;
#pragma unroll
            for (int r = 0; r < 4; ++r) {
                int row = m0 + wr * 64 + ti * 16 + (lane >> 4) * 4 + r;
                base[(size_t)row * 256 + outc] = f2bf(acc[ti][tj][r] + bias);
            }
        }
}

// ---------------------------------------------------------------------------
// Fused attention: chunk = 256 n, grid (32,16).
//   Epilogue now writes PLAIN per-chunk partials (upd_part[ch][b][2048],
//   sums_part[ch][b][8]) instead of 1M contended global atomics.
// ---------------------------------------------------------------------------
__global__ __launch_bounds__(256) void attn_fused(
    const unsigned short* __restrict__ qb, const unsigned short* __restrict__ K,
    const unsigned short* __restrict__ V,
    float* __restrict__ upd_part, float* __restrict__ sums_part) {
    __shared__ __align__(16) unsigned short qs[8 * 264];
    __shared__ __align__(16) float atf[8 * 256];
    __shared__ __align__(16) float pr[4][8 * 256];
    __shared__ float ssum[8];
    int b = blockIdx.x, ch = blockIdx.y, t = threadIdx.x;
    int wave = t >> 6, lane = t & 63;

    *(uint4*)&qs[(t >> 5) * 264 + (t & 31) * 8] = ((const uint4*)(qb + (size_t)b * 2048))[t];
    if (t < 8) ssum[t] = 0.f;
    __syncthreads();

    // ---- QK^T via MFMA: dots[s(8, pad to 16)][n = 256-chunk] ----
    {
        bf16x8 af[8];
#pragma unroll
        for (int ks = 0; ks < 8; ++ks)
            af[ks] = *(const bf16x8*)&qs[(lane & 7) * 264 + ks * 32 + (lane >> 4) * 8];
        const unsigned short* kb_ = K + ((size_t)b * 4096 + ch * 256) * 256;
#pragma unroll
        for (int nt = 0; nt < 4; ++nt) {
            int n0 = (wave * 4 + nt) * 16;
            const unsigned short* kp = kb_ + (size_t)(n0 + (lane & 15)) * 256 + (lane >> 4) * 8;
            f32x4 a = {0.f, 0.f, 0.f, 0.f};
#pragma unroll
            for (int ks = 0; ks < 8; ++ks) {
                bf16x8 bfr = *(const bf16x8*)(kp + ks * 32);
                a = __builtin_amdgcn_mfma_f32_16x16x32_bf16(af[ks], bfr, a, 0, 0, 0);
            }
            if (lane < 32) {
                int n = n0 + (lane & 15);
                int s0 = (lane >> 4) * 4;
#pragma unroll
                for (int r = 0; r < 4; ++r)
                    atf[(s0 + r) * 256 + n] = a[r] * 0.0625f;
            }
        }
    }
    __syncthreads();

    // ---- softmax over slots + per-slot sums ----
    {
        int n = t;
        float v[8];
#pragma unroll
        for (int s = 0; s < 8; ++s) v[s] = atf[s * 256 + n];
        float m = v[0];
#pragma unroll
        for (int s = 1; s < 8; ++s) m = fmaxf(m, v[s]);
        float sum = 0.f;
#pragma unroll
        for (int s = 0; s < 8; ++s) { v[s] = __expf(v[s] - m); sum += v[s]; }
        float inv = 1.0f / sum;
        float ts[8];
#pragma unroll
        for (int s = 0; s < 8; ++s) {
            float a = v[s] * inv + 1e-8f;
            atf[s * 256 + n] = a;
            ts[s] = a;
        }
#pragma unroll
        for (int s = 0; s < 8; ++s) {
#pragma unroll
            for (int off = 32; off > 0; off >>= 1)
                ts[s] += __shfl_xor(ts[s], off, 64);
        }
        if (lane == 0) {
#pragma unroll
            for (int s = 0; s < 8; ++s) atomicAdd(&ssum[s], ts[s]);
        }
    }
    __syncthreads();
    if (t < 8) sums_part[((size_t)ch * 32 + b) * 8 + t] = ssum[t];

    // ---- PV: register double-buffered V loads ----
    float ua[8][4];
#pragma unroll
    for (int s = 0; s < 8; ++s)
#pragma unroll
        for (int k = 0; k < 4; ++k) ua[s][k] = 0.f;
    const unsigned short* vb = V + ((size_t)b * 4096 + ch * 256 + wave * 64) * 256 + lane * 4;
    uint2 vv[4], vn[4];
#pragma unroll
    for (int kk = 0; kk < 4; ++kk) vv[kk] = *(const uint2*)(vb + (size_t)kk * 256);
    for (int g = 0; g < 16; ++g) {
        if (g < 15) {
            const unsigned short* nrow = vb + (size_t)(g + 1) * 1024;
#pragma unroll
            for (int kk = 0; kk < 4; ++kk) vn[kk] = *(const uint2*)(nrow + (size_t)kk * 256);
        }
        int nl = wave * 64 + g * 4;
        float4 a4[8];
#pragma unroll
        for (int s = 0; s < 8; ++s) a4[s] = *(const float4*)&atf[s * 256 + nl];
#define UPD_STEP(kk, comp)                                                     \
        {                                                                      \
            float v0 = bf2f_lo(vv[kk].x), v1 = bf2f_hi(vv[kk].x);              \
            float v2 = bf2f_lo(vv[kk].y), v3 = bf2f_hi(vv[kk].y);              \
            _Pragma("unroll")                                                  \
            for (int s = 0; s < 8; ++s) {                                      \
                float a = a4[s].comp;                                          \
                ua[s][0] += a * v0; ua[s][1] += a * v1;                        \
                ua[s][2] += a * v2; ua[s][3] += a * v3;                        \
            }                                                                  \
        }
        UPD_STEP(0, x) UPD_STEP(1, y) UPD_STEP(2, z) UPD_STEP(3, w)
#undef UPD_STEP
#pragma unroll
        for (int kk = 0; kk < 4; ++kk) vv[kk] = vn[kk];
    }
#pragma unroll
    for (int s = 0; s < 8; ++s)
        *(float4*)&pr[wave][s * 256 + lane * 4] = *(float4*)ua[s];
    __syncthreads();
    float* updp = upd_part + ((size_t)ch * 32 + b) * 2048;
    for (int i = t; i < 2048; i += 256)
        updp[i] = pr[0][i] + pr[1][i] + pr[2][i] + pr[3][i];
}

// ---------------------------------------------------------------------------
// Slot tail: 512 threads (8 waves).  Sums the 16 per-chunk partials
// (no atomics, no zeroing anywhere).
// ---------------------------------------------------------------------------
__global__ __launch_bounds__(512, 1) void slot_tail(
    const float* __restrict__ upd_part, const float* __restrict__ sums_part,
    const float* __restrict__ cur,
    const unsigned short* __restrict__ Wg, const float* __restrict__ bg,
    const float* __restrict__ g_mlp, const float* __restrict__ b_mlp,
    const unsigned short* __restrict__ W1b, const float* __restrict__ b1,
    const unsigned short* __restrict__ W2b, const float* __restrict__ b2,
    const float* __restrict__ g_slot, const float* __restrict__ b_slot,
    const unsigned short* __restrict__ Wqb, const float* __restrict__ bq,
    float* __restrict__ slots_out, unsigned short* __restrict__ qbuf,
    int do_q) {
    __shared__ float gts[8 * 1536];
    __shared__ float hn[2048];
    __shared__ float sn[2048];
    __shared__ __align__(16) unsigned short A1u[8 * 264];
    __shared__ __align__(16) unsigned short A1h[8 * 264];
    __shared__ __align__(16) unsigned short A1[8 * 264];
    __shared__ __align__(16) unsigned short A2[8 * 520];
    __shared__ float ssum8[8];
    int b = blockIdx.x, t = threadIdx.x;
    int wave = t >> 6, lane = t & 63;

    if (t < 8) {
        float s8 = 0.f;
#pragma unroll
        for (int c = 0; c < 16; ++c) s8 += sums_part[((size_t)c * 32 + b) * 8 + t];
        ssum8[t] = s8;
    }
    __syncthreads();
    for (int idx = t; idx < 2048; idx += 512) {
        float us = 0.f;
#pragma unroll
        for (int c = 0; c < 16; ++c) us += upd_part[((size_t)c * 32 + b) * 2048 + idx];
        int row = idx >> 8, d = idx & 255;
        A1u[row * 264 + d] = f2bf(us / ssum8[row]);
        A1h[row * 264 + d] = f2bf(cur[(size_t)b * 2048 + idx]);
    }
    __syncthreads();

    // ---- gates GEMM: 96 col-tiles, waves 0-3 -> u@W_ih, 4-7 -> h@W_hh ----
    {
        const unsigned short* Af = (wave < 4) ? A1u : A1h;
        bf16x8 af[8];
#pragma unroll
        for (int ks = 0; ks < 8; ++ks)
            af[ks] = *(const bf16x8*)&Af[(lane & 15) * 264 + ks * 32 + (lane >> 4) * 8];
#pragma unroll
        for (int nt = 0; nt < 12; ++nt) {
            int n0 = wave * 192 + nt * 16;
            f32x4 a = {0.f, 0.f, 0.f, 0.f};
#pragma unroll
            for (int ks = 0; ks < 8; ++ks) {
                bf16x8 bfr = *(const bf16x8*)(Wg + (size_t)(n0 + (lane & 15)) * 256 +
                                              ks * 32 + (lane >> 4) * 8);
                a = __builtin_amdgcn_mfma_f32_16x16x32_bf16(af[ks], bfr, a, 0, 0, 0);
            }
            int col = n0 + (lane & 15);
            float bs = bg[col];
#pragma unroll
            for (int r = 0; r < 4; ++r) {
                int row = (lane >> 4) * 4 + r;
                if (row < 8) gts[row * 1536 + col] = a[r] + bs;
            }
        }
    }
    __syncthreads();

    // ---- GRU combine ----
#pragma unroll
    for (int p = 0; p < 4; ++p) {
        int idx = p * 512 + t;
        int s = idx >> 8, j = idx & 255;
        const float* gr = &gts[s * 1536];
        float r  = sigf(gr[j] + gr[768 + j]);
        float z  = sigf(gr[256 + j] + gr[1024 + j]);
        float nn = tanhf(gr[512 + j] + r * gr[1280 + j]);
        float h  = cur[(size_t)b * 2048 + idx];
        hn[idx] = (1.0f - z) * nn + z * h;
    }
    __syncthreads();

    // ---- LN(mlp) -> A1, one row per wave ----
    {
        float4 g4 = *(const float4*)(g_mlp + lane * 4);
        float4 b4 = *(const float4*)(b_mlp + lane * 4);
        int s = wave;
        float4 x = *(const float4*)&hn[s * 256 + lane * 4];
        float sm = x.x + x.y + x.z + x.w;
        float sq = x.x * x.x + x.y * x.y + x.z * x.z + x.w * x.w;
#pragma unroll
        for (int off = 32; off > 0; off >>= 1) {
            sm += __shfl_xor(sm, off, 64);
            sq += __shfl_xor(sq, off, 64);
        }
        float mean = sm * (1.0f / 256.0f);
        float rstd = rsqrtf(sq * (1.0f / 256.0f) - mean * mean + 1e-3f);
        uint2 o;
        o.x = (uint32_t)f2bf((x.x - mean) * rstd * g4.x + b4.x) |
              ((uint32_t)f2bf((x.y - mean) * rstd * g4.y + b4.y) << 16);
        o.y = (uint32_t)f2bf((x.z - mean) * rstd * g4.z + b4.z) |
              ((uint32_t)f2bf((x.w - mean) * rstd * g4.w + b4.w) << 16);
        *(uint2*)&A1[s * 264 + lane * 4] = o;
    }
    __syncthreads();

    // ---- MLP1: A2 = relu(A1 @ W1^T + b1), 32 tiles / 8 waves ----
    {
        bf16x8 af[8];
#pragma unroll
        for (int ks = 0; ks < 8; ++ks)
            af[ks] = *(const bf16x8*)&A1[(lane & 15) * 264 + ks * 32 + (lane >> 4) * 8];
#pragma unroll
        for (int nt = 0; nt < 4; ++nt) {
            int n0 = (wave * 4 + nt) * 16;
            f32x4 a = {0.f, 0.f, 0.f, 0.f};
#pragma unroll
            for (int ks = 0; ks < 8; ++ks) {
                bf16x8 bfr = *(const bf16x8*)(W1b + (size_t)(n0 + (lane & 15)) * 256 +
                                              ks * 32 + (lane >> 4) * 8);
                a = __builtin_amdgcn_mfma_f32_16x16x32_bf16(af[ks], bfr, a, 0, 0, 0);
            }
            int col = n0 + (lane & 15);
            float bs = b1[col];
#pragma unroll
            for (int r = 0; r < 4; ++r) {
                int row = (lane >> 4) * 4 + r;
                if (row < 8) A2[row * 520 + col] = f2bf(fmaxf(a[r] + bs, 0.f));
            }
        }
    }
    __syncthreads();

    // ---- MLP2: sn = A2 @ W2^T + b2 + hn, 16 tiles / 8 waves ----
    {
        bf16x8 af[16];
#pragma unroll
        for (int ks = 0; ks < 16; ++ks)
            af[ks] = *(const bf16x8*)&A2[(lane & 15) * 520 + ks * 32 + (lane >> 4) * 8];
#pragma unroll
        for (int nt = 0; nt < 2; ++nt) {
            int n0 = (wave * 2 + nt) * 16;
            f32x4 a = {0.f, 0.f, 0.f, 0.f};
#pragma unroll
            for (int ks = 0; ks < 16; ++ks) {
                bf16x8 bfr = *(const bf16x8*)(W2b + (size_t)(n0 + (lane & 15)) * 512 +
                                              ks * 32 + (lane >> 4) * 8);
                a = __builtin_amdgcn_mfma_f32_16x16x32_bf16(af[ks], bfr, a, 0, 0, 0);
            }
            int col = n0 + (lane & 15);
            float bs = b2[col];
#pragma unroll
            for (int r = 0; r < 4; ++r) {
                int row = (lane >> 4) * 4 + r;
                if (row < 8) {
                    float v = a[r] + bs + hn[row * 256 + col];
                    sn[row * 256 + col] = v;
                    slots_out[((size_t)b * 8 + row) * 256 + col] = v;
                }
            }
        }
    }
    if (!do_q) return;
    __syncthreads();

    // ---- LN(slot) on sn -> A1 ----
    {
        float4 g4 = *(const float4*)(g_slot + lane * 4);
        float4 b4 = *(const float4*)(b_slot + lane * 4);
        int s = wave;
        float4 x = *(const float4*)&sn[s * 256 + lane * 4];
        float sm = x.x + x.y + x.z + x.w;
        float sq = x.x * x.x + x.y * x.y + x.z * x.z + x.w * x.w;
#pragma unroll
        for (int off = 32; off > 0; off >>= 1) {
            sm += __shfl_xor(sm, off, 64);
            sq += __shfl_xor(sq, off, 64);
        }
        float mean = sm * (1.0f / 256.0f);
        float rstd = rsqrtf(sq * (1.0f / 256.0f) - mean * mean + 1e-3f);
        uint2 o;
        o.x = (uint32_t)f2bf((x.x - mean) * rstd * g4.x + b4.x) |
              ((uint32_t)f2bf((x.y - mean) * rstd * g4.y + b4.y) << 16);
        o.y = (uint32_t)f2bf((x.z - mean) * rstd * g4.z + b4.z) |
              ((uint32_t)f2bf((x.w - mean) * rstd * g4.w + b4.w) << 16);
        *(uint2*)&A1[s * 264 + lane * 4] = o;
    }
    __syncthreads();

    // ---- q = A1 @ Wq^T + bq, 16 tiles / 8 waves ----
    {
        bf16x8 af[8];
#pragma unroll
        for (int ks = 0; ks < 8; ++ks)
            af[ks] = *(const bf16x8*)&A1[(lane & 15) * 264 + ks * 32 + (lane >> 4) * 8];
#pragma unroll
        for (int nt = 0; nt < 2; ++nt) {
            int n0 = (wave * 2 + nt) * 16;
            f32x4 a = {0.f, 0.f, 0.f, 0.f};
#pragma unroll
            for (int ks = 0; ks < 8; ++ks) {
                bf16x8 bfr = *(const bf16x8*)(Wqb + (size_t)(n0 + (lane & 15)) * 256 +
                                              ks * 32 + (lane >> 4) * 8);
                a = __builtin_amdgcn_mfma_f32_16x16x32_bf16(af[ks], bfr, a, 0, 0, 0);
            }
            int col = n0 + (lane & 15);
            float bs = bq[col];
#pragma unroll
            for (int r = 0; r < 4; ++r) {
                int row = (lane >> 4) * 4 + r;
                if (row < 8)
                    qbuf[((size_t)b * 8 + row) * 256 + col] = f2bf(a[r] + bs);
            }
        }
    }
}

// ---------------------------------------------------------------------------
extern "C" void kernel_launch(void* const* d_in, const int* in_sizes, int n_in,
                              void* d_out, int out_size, void* d_ws, size_t ws_size,
                              hipStream_t stream) {
    const float* inputs    = (const float*)d_in[0];
    const float* slots_in  = (const float*)d_in[1];
    const float* ln_in_g   = (const float*)d_in[3];
    const float* ln_in_b   = (const float*)d_in[4];
    const float* ln_slot_g = (const float*)d_in[5];
    const float* ln_slot_b = (const float*)d_in[6];
    const float* ln_mlp_g  = (const float*)d_in[7];
    const float* ln_mlp_b  = (const float*)d_in[8];
    const float* Wq   = (const float*)d_in[9];
    const float* bq   = (const float*)d_in[10];
    const float* Wk   = (const float*)d_in[11];
    const float* bk   = (const float*)d_in[12];
    const float* Wv   = (const float*)d_in[13];
    const float* bv   = (const float*)d_in[14];
    const float* W_ih = (const float*)d_in[15];
    const float* b_ih = (const float*)d_in[16];
    const float* W_hh = (const float*)d_in[17];
    const float* b_hh = (const float*)d_in[18];
    const float* W1   = (const float*)d_in[19];
    const float* b1   = (const float*)d_in[20];
    const float* W2   = (const float*)d_in[21];
    const float* b2   = (const float*)d_in[22];

    char* p = (char*)d_ws;
    size_t off = 0;
    auto take = [&](size_t bytes) -> char* {
        char* r = p + off;
        off += (bytes + 255) & ~(size_t)255;
        return r;
    };
    unsigned short* xbf  = (unsigned short*)take((size_t)131072 * 256 * 2);
    unsigned short* Kb   = (unsigned short*)take((size_t)131072 * 256 * 2);
    unsigned short* Vb   = (unsigned short*)take((size_t)131072 * 256 * 2);
    unsigned short* Wkv  = (unsigned short*)take(131072 * 2);
    unsigned short* Wg   = (unsigned short*)take(393216 * 2);
    unsigned short* W1b  = (unsigned short*)take(131072 * 2);
    unsigned short* W2b  = (unsigned short*)take(131072 * 2);
    unsigned short* Wqb  = (unsigned short*)take(65536 * 2);
    float* bkv   = (float*)take(512 * 4);
    float* bg    = (float*)take(1536 * 4);
    unsigned short* qbuf = (unsigned short*)take(65536 * 2);
    float* upd_part  = (float*)take((size_t)16 * 32 * 2048 * 4);  // 4 MB partials
    float* sums_part = (float*)take((size_t)16 * 32 * 8 * 4);
    float* sA    = (float*)take(65536 * 4);
    float* sB    = (float*)take(65536 * 4);

    prep_k<<<11552, 256, 0, stream>>>(inputs, ln_in_g, ln_in_b, xbf,
                                      Wk, Wv, W_ih, W_hh, W1, W2,
                                      bk, bv, b_ih, b_hh,
                                      Wkv, Wg, W1b, W2b, Wqb, bkv, bg,
                                      slots_in, ln_slot_g, ln_slot_b, Wq, bq, qbuf);
    gemm_kv<<<4096, 256, 0, stream>>>(xbf, Wkv, bkv, Kb, Vb);

    const float* cur = slots_in;
    float* nxt[3] = {sA, sB, (float*)d_out};
    for (int it = 0; it < 3; ++it) {
        attn_fused<<<dim3(32, 16), 256, 0, stream>>>(qbuf, Kb, Vb, upd_part, sums_part);
        slot_tail<<<32, 512, 0, stream>>>(upd_part, sums_part, cur, Wg, bg,
                                          ln_mlp_g, ln_mlp_b, W1b, b1, W2b, b2,
                                          ln_slot_g, ln_slot_b, Wqb, bq,
                                          nxt[it], qbuf, it < 2 ? 1 : 0);
        cur = nxt[it];
    }
    (void)in_sizes; (void)n_in; (void)out_size; (void)ws_size;
}